// Round 9
// baseline (1037.883 us; speedup 1.0000x reference)
//
#include <hip/hip_runtime.h>
#include <cstdint>
#include <cstddef>

#define NNODES 20000
#define NEDGES 320000
#define HID 512
#define EDIM 64
#define KFEAT (2*HID + EDIM)   // 1088

typedef __bf16 bf16x8 __attribute__((ext_vector_type(8)));
typedef short short8 __attribute__((ext_vector_type(8)));
typedef float f32x4 __attribute__((ext_vector_type(4)));

#define AM_NODE 1
#define AM_DIR  2
#define EP_BF16    0   // +bias, mish, bf16 store
#define EP_F32     2   // +bias, raw f32 store
#define EP_BF16L   3   // no bias, no mish, bf16 store
#define EP_SCATSEG 4   // +bias, mish, dst-segmented atomicAdd into Cf

__device__ __forceinline__ uint16_t f2bf(float f){
  uint32_t u = __float_as_uint(f);
  u += 0x7FFFu + ((u >> 16) & 1u);
  return (uint16_t)(u >> 16);
}
__device__ __forceinline__ float bf2f(uint16_t h){
  return __uint_as_float((uint32_t)h << 16);
}
// mish(x) = x * tanh(softplus(x)) = x * (e^2+2e)/(e^2+2e+2), e = exp(x)
__device__ __forceinline__ float mishf(float v){
  float e = __expf(fminf(v, 18.f));
  float n = e * (e + 2.f);
  return v * __fdividef(n, n + 2.f);
}
__device__ __forceinline__ void gl_lds16(const void* g, void* l){
  __builtin_amdgcn_global_load_lds(
      (const __attribute__((address_space(1))) uint32_t*)g,
      (__attribute__((address_space(3))) uint32_t*)l, 16, 0, 0);
}

// ---------------- index dtype detect / normalize ----------------
__global__ void detect_idx(const int* __restrict__ e, int* __restrict__ flag){
  int i = blockIdx.x * 256 + threadIdx.x;   // probe first 16384 pairs
  if (e[2*i + 1] != 0) atomicOr(flag, 1);   // flag=1 -> int32 layout
}
__global__ void norm_idx(const int* __restrict__ e, const int* __restrict__ flag,
                         int* __restrict__ s, int* __restrict__ d){
  int i = blockIdx.x * 256 + threadIdx.x;
  if (i >= NEDGES) return;
  int sv, dv;
  if (*flag){ sv = e[i];     dv = e[NEDGES + i]; }
  else      { sv = e[2*i];   dv = e[2*NEDGES + 2*i]; }   // int64 lo words
  sv = sv < 0 ? 0 : (sv > NNODES-1 ? NNODES-1 : sv);
  dv = dv < 0 ? 0 : (dv > NNODES-1 ? NNODES-1 : dv);
  s[i] = sv; d[i] = dv;
}

// ---------------- counting sort by dst (single permutation) ----------------
__global__ void hist_k(const int* __restrict__ d, int* __restrict__ cnt){
  int i = blockIdx.x * 256 + threadIdx.x;
  if (i < NEDGES) atomicAdd(&cnt[d[i]], 1);
}
__global__ __launch_bounds__(256)
void scan_k(const int* __restrict__ cnt, int* __restrict__ rp, int* __restrict__ cur){
  const int SEG = (NNODES + 255) / 256;
  const int t = threadIdx.x;
  const int lo = t * SEG;
  const int hi = (lo + SEG < NNODES) ? lo + SEG : NNODES;
  int s = 0;
  for (int i = lo; i < hi; ++i) s += cnt[i];
  __shared__ int sh[256];
  sh[t] = s; __syncthreads();
  for (int o = 1; o < 256; o <<= 1){
    int v = (t >= o) ? sh[t - o] : 0;
    __syncthreads();
    sh[t] += v;
    __syncthreads();
  }
  int pre = t ? sh[t-1] : 0;
  for (int i = lo; i < hi; ++i){
    rp[i] = pre; cur[i] = pre; pre += cnt[i];
  }
  if (t == 255) rp[NNODES] = sh[255];
}
// ONE permutation: sorted position p gets src id AND original edge id.
__global__ void permute_k(const int* __restrict__ srcN, const int* __restrict__ dstN,
                          int* __restrict__ cur, int* __restrict__ srcS,
                          int* __restrict__ eidx){
  int i = blockIdx.x * 256 + threadIdx.x;
  if (i < NEDGES){
    int d = dstN[i];
    int p = atomicAdd(&cur[d], 1);
    srcS[p] = srcN[i];
    eidx[p] = i;
  }
}
__global__ void fill_dstS(const int* __restrict__ rp, int* __restrict__ dstS){
  int n = blockIdx.x;
  int lo = rp[n], hi = rp[n+1];
  for (int e = lo + threadIdx.x; e < hi; e += 64) dstS[e] = n;
}

// ---------------- casts ----------------
__global__ void cast_bf16_vec(const float4* __restrict__ in, ushort4* __restrict__ out, int n4){
  int i = blockIdx.x * 256 + threadIdx.x;
  if (i < n4){
    float4 v = in[i];
    ushort4 o; o.x = f2bf(v.x); o.y = f2bf(v.y); o.z = f2bf(v.z); o.w = f2bf(v.w);
    out[i] = o;
  }
}
__global__ void transpose_cast(const float* __restrict__ W, uint16_t* __restrict__ WT, int K, int N){
  int k = blockIdx.x * 256 + threadIdx.x;
  int n = blockIdx.y;
  if (k < K) WT[(size_t)n * K + k] = f2bf(W[(size_t)k * N + n]);
}

// ---------------- fused MFMA GEMM (128x128 tile, BK=64, 4 waves) ----------------
// Grid: blockIdx.x = COL tile (fast -> consecutive blocks share the A panel),
//       blockIdx.y = ROW tile.
// AM_NODE: row gm = [xb[gm] | aggb[gm]]  (K = 1024)
// AM_DIR : row-major A0, stride KTOT
// BPQ=1  : B^T row n -> w1t + (n&511)*bstr + (n>>9)*512  (fused P|Q, N=1024)
// EP_SCATSEG: dst-segmented fp32 atomicAdd into Cf[dstI[row]][col]
template<int AMODE, int EPI, int KTOT, int BPQ>
__global__ __launch_bounds__(256, 2)
void gemm_k(const uint16_t* __restrict__ A0, const uint16_t* __restrict__ A1,
            const uint16_t* __restrict__ BT, const float* __restrict__ bias,
            uint16_t* __restrict__ Cb, float* __restrict__ Cf,
            const int* __restrict__ dstI,
            int bstr, int cstr, int m0base, int M, int crowOff)
{
  __shared__ __align__(16) char smem[32768];
  char* As = smem;
  char* Bs = smem + 16384;
  const int t = threadIdx.x;
  const int m0 = m0base + blockIdx.y * 128;
  const int n0 = blockIdx.x * 128;
  const int srow = t >> 3;
  const int c8   = t & 7;
  const int scol = ((c8 ^ (srow & 7)) << 3);
  const int ldst = srow * 128 + c8 * 16;

  const uint16_t* as0[4]; const uint16_t* as1[4];
  #pragma unroll
  for (int i = 0; i < 4; ++i){
    int gm = m0 + srow + 32*i;
    if (gm > M - 1) gm = M - 1;
    if (AMODE == AM_NODE){
      as0[i] = A0 + (size_t)gm * HID;
      as1[i] = A1 + (size_t)gm * HID;
    } else {
      as0[i] = A0 + (size_t)gm * KTOT;
      as1[i] = A0;
    }
  }
  const uint16_t* brow[4];
  #pragma unroll
  for (int i = 0; i < 4; ++i){
    int nr = n0 + srow + 32*i;
    if (BPQ) brow[i] = BT + (size_t)(nr & (HID-1))*bstr + (nr >> 9)*HID;
    else     brow[i] = BT + (size_t)nr*bstr;
  }

  const int lane = t & 63;
  const int wv = t >> 6;
  const int wm = (wv >> 1) * 64;
  const int wn = (wv & 1) * 64;
  const int l15 = lane & 15;
  const int lk16 = (lane >> 4) << 4;
  const int swz = (l15 & 7) << 4;

  f32x4 acc[4][4] = {};

  const int NK = KTOT / 64;
  for (int kk = 0; kk < NK; ++kk){
    const int k0 = kk * 64;
    #pragma unroll
    for (int i = 0; i < 4; ++i){
      const uint16_t* g;
      if (AMODE == AM_NODE){
        g = (k0 < HID) ? as0[i] + (k0 + scol) : as1[i] + (k0 - HID + scol);
      } else {
        g = as0[i] + (k0 + scol);
      }
      gl_lds16(g, As + i*4096 + ldst);
    }
    #pragma unroll
    for (int i = 0; i < 4; ++i)
      gl_lds16(brow[i] + (k0 + scol), Bs + i*4096 + ldst);
    __syncthreads();
    #pragma unroll
    for (int ks = 0; ks < 2; ++ks){
      bf16x8 af[4], bfr[4];
      #pragma unroll
      for (int i = 0; i < 4; ++i){
        const int ar = wm + i*16 + l15;
        af[i] = *(const bf16x8*)(As + ar*128 + ((ks*64 + lk16) ^ swz));
      }
      #pragma unroll
      for (int j = 0; j < 4; ++j){
        const int br = wn + j*16 + l15;
        bfr[j] = *(const bf16x8*)(Bs + br*128 + ((ks*64 + lk16) ^ swz));
      }
      #pragma unroll
      for (int i = 0; i < 4; ++i)
        #pragma unroll
        for (int j = 0; j < 4; ++j)
          acc[i][j] = __builtin_amdgcn_mfma_f32_16x16x32_bf16(af[i], bfr[j], acc[i][j], 0, 0, 0);
    }
    __syncthreads();
  }

  #pragma unroll
  for (int i = 0; i < 4; ++i){
    const int rb = wm + i*16 + ((lane >> 4) << 2);
    int dstv[4];
    if (EPI == EP_SCATSEG){
      #pragma unroll
      for (int r = 0; r < 4; ++r){
        int grow = m0 + rb + r;
        dstv[r] = (grow < M) ? dstI[grow] : -1;
      }
    }
    #pragma unroll
    for (int j = 0; j < 4; ++j){
      const int gcol = n0 + wn + j*16 + l15;
      const float bv = (EPI == EP_BF16L) ? 0.f : bias[gcol];
      if (EPI == EP_SCATSEG){
        float part = 0.f; int cur = dstv[0];
        #pragma unroll
        for (int r = 0; r < 4; ++r){
          int grow = m0 + rb + r;
          if (grow < M){
            float v = mishf(acc[i][j][r] + bv);
            if (dstv[r] != cur){
              if (cur >= 0) atomicAdd(&Cf[(size_t)cur * HID + gcol], part);
              part = 0.f; cur = dstv[r];
            }
            part += v;
          }
        }
        if (cur >= 0) atomicAdd(&Cf[(size_t)cur * HID + gcol], part);
      } else {
        #pragma unroll
        for (int r = 0; r < 4; ++r){
          const int grow = m0 + rb + r;
          if (grow < M){
            float v = acc[i][j][r] + bv;
            if (EPI == EP_BF16){
              Cb[(size_t)(grow - crowOff) * cstr + gcol] = f2bf(mishf(v));
            } else if (EPI == EP_BF16L){
              Cb[(size_t)(grow - crowOff) * cstr + gcol] = f2bf(v);
            } else {
              Cf[(size_t)grow * cstr + gcol] = v;
            }
          }
        }
      }
    }
  }
}

// ---------------- EH: h = mish(ea@W1c + P[src] + Q[dst] + b1) ----------------
// 256 threads = 4 waves; block = 32 edges x 512 cols; wave wv owns cols [wv*128, +128).
// K = 64 (2 MFMA k-steps), acc[2][8]. A-frags direct bf16x8 loads from eab.
// Epilogue: stage acc quarter-tile in wave-private LDS (XOR-bit6 swizzle), read back
// row-linear -> P/Q/h coalesced. PQb layout: [n][1024], P = 0..511, Q = 512..1023.
__global__ __launch_bounds__(256, 4)
void eh_k(const uint16_t* __restrict__ eab, const uint16_t* __restrict__ PQb,
          const int* __restrict__ idx,
          const uint16_t* __restrict__ w1t, const float* __restrict__ b1,
          uint16_t* __restrict__ hb, int m0base, int crowOff)
{
  __shared__ __align__(16) char smem[32768];   // 4 waves x 8KB (16 rows x 512B)
  const int t = threadIdx.x;
  const int m0 = m0base + blockIdx.x * 32;
  const int lane = t & 63;
  const int wv = t >> 6;
  const int l15 = lane & 15;
  const int lg = lane >> 4;                    // 0..3
  const int* srcS = idx;
  const int* dstS = idx + NEDGES;
  const int* eidx = idx + 2*NEDGES;

  int eidxr[2];
  #pragma unroll
  for (int fr = 0; fr < 2; ++fr) eidxr[fr] = eidx[m0 + fr*16 + l15];

  f32x4 acc[2][8] = {};

  #pragma unroll
  for (int ks = 0; ks < 2; ++ks){
    bf16x8 bF[8];
    #pragma unroll
    for (int fc = 0; fc < 8; ++fc){
      int n = wv*128 + fc*16 + l15;
      bF[fc] = *(const bf16x8*)(w1t + (size_t)n*KFEAT + 2*HID + ks*32 + lg*8);
    }
    #pragma unroll
    for (int fr = 0; fr < 2; ++fr){
      bf16x8 av = *(const bf16x8*)(eab + (size_t)eidxr[fr]*EDIM + ks*32 + lg*8);
      #pragma unroll
      for (int fc = 0; fc < 8; ++fc)
        acc[fr][fc] = __builtin_amdgcn_mfma_f32_16x16x32_bf16(av, bF[fc], acc[fr][fc], 0, 0, 0);
    }
  }

  // epilogue: per fr quarter (16 rows x 128 cols), wave-private slab
  char* slab = smem + wv*8192;
  const float4 b1v0 = *(const float4*)(b1 + wv*128 + l15*4);
  const float4 b1v1 = *(const float4*)(b1 + wv*128 + 64 + l15*4);
  #pragma unroll
  for (int fr = 0; fr < 2; ++fr){
    #pragma unroll
    for (int fc = 0; fc < 8; ++fc){
      #pragma unroll
      for (int r = 0; r < 4; ++r){
        int row = lg*4 + r;                    // row>>2 == lg
        int cb = ((fc*16 + l15)*4) ^ ((lg & 1) << 6);
        *(float*)(slab + row*512 + cb) = acc[fr][fc][r];
      }
    }
    asm volatile("s_waitcnt lgkmcnt(0)" ::: "memory");
    __builtin_amdgcn_sched_barrier(0);
    #pragma unroll
    for (int i = 0; i < 4; ++i){
      int row = i*4 + lg;                      // row>>2 == i
      int grow = m0 + fr*16 + row;
      int s = srcS[grow];
      int d = dstS[grow];
      float4 v0 = *(const float4*)(slab + row*512 + ((l15*16) ^ ((i & 1) << 6)));
      float4 v1 = *(const float4*)(slab + row*512 + ((256 + l15*16) ^ ((i & 1) << 6)));
      ushort4 p0 = *(const ushort4*)(PQb + (size_t)s*1024 + wv*128 + l15*4);
      ushort4 p1 = *(const ushort4*)(PQb + (size_t)s*1024 + wv*128 + 64 + l15*4);
      ushort4 q0 = *(const ushort4*)(PQb + (size_t)d*1024 + 512 + wv*128 + l15*4);
      ushort4 q1 = *(const ushort4*)(PQb + (size_t)d*1024 + 512 + wv*128 + 64 + l15*4);
      ushort4 h0, h1;
      h0.x = f2bf(mishf(v0.x + bf2f(p0.x) + bf2f(q0.x) + b1v0.x));
      h0.y = f2bf(mishf(v0.y + bf2f(p0.y) + bf2f(q0.y) + b1v0.y));
      h0.z = f2bf(mishf(v0.z + bf2f(p0.z) + bf2f(q0.z) + b1v0.z));
      h0.w = f2bf(mishf(v0.w + bf2f(p0.w) + bf2f(q0.w) + b1v0.w));
      h1.x = f2bf(mishf(v1.x + bf2f(p1.x) + bf2f(q1.x) + b1v1.x));
      h1.y = f2bf(mishf(v1.y + bf2f(p1.y) + bf2f(q1.y) + b1v1.y));
      h1.z = f2bf(mishf(v1.z + bf2f(p1.z) + bf2f(q1.z) + b1v1.z));
      h1.w = f2bf(mishf(v1.w + bf2f(p1.w) + bf2f(q1.w) + b1v1.w));
      size_t hrow = (size_t)(grow - crowOff) * HID + wv*128;
      *(ushort4*)(hb + hrow + l15*4) = h0;
      *(ushort4*)(hb + hrow + 64 + l15*4) = h1;
    }
    asm volatile("s_waitcnt lgkmcnt(0)" ::: "memory");
    __builtin_amdgcn_sched_barrier(0);
  }
}

// ---------------- residual + LayerNorm ----------------
__global__ __launch_bounds__(128)
void resid_ln(const float* __restrict__ x, const float* __restrict__ ob,
              const float* __restrict__ gamma, const float* __restrict__ beta,
              float* __restrict__ y){
  const int row = blockIdx.x;
  const int t = threadIdx.x;
  const float4 xv = ((const float4*)(x + (size_t)row * HID))[t];
  const float4 ov = ((const float4*)(ob + (size_t)row * HID))[t];
  float4 s4;
  s4.x = xv.x + ov.x; s4.y = xv.y + ov.y; s4.z = xv.z + ov.z; s4.w = xv.w + ov.w;
  float s = s4.x + s4.y + s4.z + s4.w;
  float q = s4.x*s4.x + s4.y*s4.y + s4.z*s4.z + s4.w*s4.w;
  #pragma unroll
  for (int o = 32; o; o >>= 1){
    s += __shfl_xor(s, o, 64);
    q += __shfl_xor(q, o, 64);
  }
  __shared__ float ss[2], qq[2];
  if ((t & 63) == 0){ ss[t >> 6] = s; qq[t >> 6] = q; }
  __syncthreads();
  const float S = ss[0] + ss[1], Q = qq[0] + qq[1];
  const float mu = S * (1.0f / HID);
  const float var = Q * (1.0f / HID) - mu * mu;
  const float inv = rsqrtf(var + 1e-5f);
  const float4 g = ((const float4*)gamma)[t];
  const float4 b = ((const float4*)beta)[t];
  float4 o;
  o.x = (s4.x - mu) * inv * g.x + b.x;
  o.y = (s4.y - mu) * inv * g.y + b.y;
  o.z = (s4.z - mu) * inv * g.z + b.z;
  o.w = (s4.w - mu) * inv * g.w + b.w;
  ((float4*)(y + (size_t)row * HID))[t] = o;
}

extern "C" void kernel_launch(void* const* d_in, const int* in_sizes, int n_in,
                              void* d_out, int out_size, void* d_ws, size_t ws_size,
                              hipStream_t stream)
{
  const float* x    = (const float*)d_in[0];
  const int*   ei   = (const int*)d_in[1];
  const float* ea   = (const float*)d_in[2];
  const float* W1   = (const float*)d_in[3];
  const float* b1   = (const float*)d_in[4];
  const float* W2   = (const float*)d_in[5];
  const float* b2   = (const float*)d_in[6];
  const float* W3   = (const float*)d_in[7];
  const float* b3   = (const float*)d_in[8];
  const float* W4   = (const float*)d_in[9];
  const float* b4   = (const float*)d_in[10];
  const float* gmm  = (const float*)d_in[11];
  const float* bet  = (const float*)d_in[12];
  float* out = (float*)d_out;

  uint8_t* w = (uint8_t*)d_ws;
  size_t off = 0;
  auto alloc = [&](size_t bytes) -> void* {
    void* p = w + off;
    off += (bytes + 255) & ~(size_t)255;
    return p;
  };
  uint16_t* xb   = (uint16_t*)alloc((size_t)NNODES*HID*2);
  uint16_t* w1t  = (uint16_t*)alloc((size_t)HID*KFEAT*2);
  uint16_t* w2t  = (uint16_t*)alloc((size_t)HID*HID*2);
  uint16_t* w3t  = (uint16_t*)alloc((size_t)HID*1024*2);
  uint16_t* w4t  = (uint16_t*)alloc((size_t)HID*HID*2);
  uint16_t* PQb  = (uint16_t*)alloc((size_t)NNODES*1024*2);   // [n][1024]: P|Q
  float*    agg  = (float*)alloc((size_t)NNODES*HID*4);
  uint16_t* aggb = (uint16_t*)alloc((size_t)NNODES*HID*2);
  uint16_t* ub   = (uint16_t*)alloc((size_t)NNODES*HID*2);
  float*    outf = (float*)alloc((size_t)NNODES*HID*4);
  int*      srcN = (int*)alloc((size_t)NEDGES*4);
  int*      dstN = (int*)alloc((size_t)NEDGES*4);
  int*      idxS = (int*)alloc((size_t)NEDGES*4*3);  // [srcS | dstS | eidx]
  int*      cnt  = (int*)alloc((size_t)NNODES*4);
  int*      rp   = (int*)alloc((size_t)(NNODES+1)*4);
  int*      cur  = (int*)alloc((size_t)NNODES*4);
  int*      flag = (int*)alloc(256);
  int*      srcS = idxS;
  int*      dstS = idxS + NEDGES;
  int*      eidx = idxS + 2*NEDGES;

  // eab (bf16 edge_attr, 40.96 MB) aliases outf (40.96 MB): eab is dead before
  // GEMM4 writes outf (stream-ordered), so no extra workspace is consumed.
  uint16_t* eab = (uint16_t*)outf;

  size_t remain = (ws_size > off) ? ws_size - off : 0;
  size_t maxChunk = remain / ((size_t)HID*2);      // hb only (msgb eliminated)
  long long chunkE = (long long)(maxChunk & ~(size_t)127);
  if (chunkE > NEDGES) chunkE = NEDGES;
  if (chunkE < 128) chunkE = 128;
  uint16_t* hb = (uint16_t*)alloc((size_t)chunkE*HID*2);

  hipMemsetAsync(agg, 0, (size_t)NNODES*HID*4, stream);
  hipMemsetAsync(cnt, 0, (size_t)NNODES*4, stream);
  hipMemsetAsync(flag, 0, 4, stream);

  detect_idx<<<64, 256, 0, stream>>>(ei, flag);
  norm_idx<<<(NEDGES+255)/256, 256, 0, stream>>>(ei, flag, srcN, dstN);
  hist_k<<<(NEDGES+255)/256, 256, 0, stream>>>(dstN, cnt);
  scan_k<<<1, 256, 0, stream>>>(cnt, rp, cur);
  permute_k<<<(NEDGES+255)/256, 256, 0, stream>>>(srcN, dstN, cur, srcS, eidx);
  fill_dstS<<<NNODES, 64, 0, stream>>>(rp, dstS);

  cast_bf16_vec<<<(NNODES*HID/4+255)/256, 256, 0, stream>>>((const float4*)x, (ushort4*)xb, NNODES*HID/4);
  cast_bf16_vec<<<(NEDGES*EDIM/4+255)/256, 256, 0, stream>>>((const float4*)ea, (ushort4*)eab, NEDGES*EDIM/4);

  transpose_cast<<<dim3((KFEAT+255)/256, HID), 256, 0, stream>>>(W1, w1t, KFEAT, HID);
  transpose_cast<<<dim3((HID+255)/256,   HID), 256, 0, stream>>>(W2, w2t, HID, HID);
  transpose_cast<<<dim3((1024+255)/256,  HID), 256, 0, stream>>>(W3, w3t, 1024, HID);
  transpose_cast<<<dim3((HID+255)/256,   HID), 256, 0, stream>>>(W4, w4t, HID, HID);

  // Fused P|Q = x @ [W1a | W1b]  (N=1024, bf16 output, no bias/act)
  // grid: (col tiles fast, row tiles slow) -> A panel fetched once
  dim3 gpq(1024/128, (NNODES+127)/128);
  gemm_k<AM_DIR, EP_BF16L, HID, 1><<<gpq, 256, 0, stream>>>(
      xb, nullptr, w1t, b1, PQb, nullptr, nullptr, KFEAT, 1024, 0, NNODES, 0);

  for (long long e0 = 0; e0 < NEDGES; e0 += chunkE){
    int ce = (int)((NEDGES - e0 < chunkE) ? (NEDGES - e0) : chunkE);
    // EH: h = mish(ea@W1c + P[src] + Q[dst] + b1) -> hb (chunk-local)
    eh_k<<<(ce+31)/32, 256, 0, stream>>>(eab, PQb, idxS, w1t, b1, hb, (int)e0, (int)e0);
    // GEMM2 + fused segment-scatter: agg[dst] += mish(hb @ W2 + b2)
    dim3 g2(HID/128, (ce+127)/128);
    gemm_k<AM_DIR, EP_SCATSEG, HID, 0><<<g2, 256, 0, stream>>>(
        hb, nullptr, w2t, b2, nullptr, agg, dstS + e0, HID, HID, 0, ce, 0);
  }

  cast_bf16_vec<<<(NNODES*HID/4+255)/256, 256, 0, stream>>>((const float4*)agg, (ushort4*)aggb, NNODES*HID/4);

  dim3 g3(HID/128, (NNODES+127)/128);
  gemm_k<AM_NODE, EP_BF16, 1024, 0><<<g3, 256, 0, stream>>>(
      xb, aggb, w3t, b3, ub, nullptr, nullptr, 1024, HID, 0, NNODES, 0);
  gemm_k<AM_DIR, EP_F32, HID, 0><<<g3, 256, 0, stream>>>(
      ub, nullptr, w4t, b4, nullptr, outf, nullptr, HID, HID, 0, NNODES, 0);

  resid_ln<<<NNODES, 128, 0, stream>>>(x, outf, gmm, bet, out);
}

// Round 10
// 938.789 us; speedup vs baseline: 1.1056x; 1.1056x over previous
//
#include <hip/hip_runtime.h>
#include <cstdint>
#include <cstddef>

#define NNODES 20000
#define NEDGES 320000
#define HID 512
#define EDIM 64
#define KFEAT (2*HID + EDIM)   // 1088

typedef __bf16 bf16x8 __attribute__((ext_vector_type(8)));
typedef short short8 __attribute__((ext_vector_type(8)));
typedef float f32x4 __attribute__((ext_vector_type(4)));

#define AM_NODE 1
#define AM_DIR  2
#define EP_BF16    0   // +bias, mish, bf16 store
#define EP_F32     2   // +bias, raw f32 store
#define EP_BF16L   3   // no bias, no mish, bf16 store

__device__ __forceinline__ uint16_t f2bf(float f){
  uint32_t u = __float_as_uint(f);
  u += 0x7FFFu + ((u >> 16) & 1u);
  return (uint16_t)(u >> 16);
}
__device__ __forceinline__ float bf2f(uint16_t h){
  return __uint_as_float((uint32_t)h << 16);
}
// mish(x) = x * tanh(softplus(x)) = x * (e^2+2e)/(e^2+2e+2), e = exp(x)
__device__ __forceinline__ float mishf(float v){
  float e = __expf(fminf(v, 18.f));
  float n = e * (e + 2.f);
  return v * __fdividef(n, n + 2.f);
}
__device__ __forceinline__ void gl_lds16(const void* g, void* l){
  __builtin_amdgcn_global_load_lds(
      (const __attribute__((address_space(1))) uint32_t*)g,
      (__attribute__((address_space(3))) uint32_t*)l, 16, 0, 0);
}

// ---------------- index dtype detect / normalize ----------------
__global__ void detect_idx(const int* __restrict__ e, int* __restrict__ flag){
  int i = blockIdx.x * 256 + threadIdx.x;   // probe first 16384 pairs
  if (e[2*i + 1] != 0) atomicOr(flag, 1);   // flag=1 -> int32 layout
}
__global__ void norm_idx(const int* __restrict__ e, const int* __restrict__ flag,
                         int* __restrict__ s, int* __restrict__ d){
  int i = blockIdx.x * 256 + threadIdx.x;
  if (i >= NEDGES) return;
  int sv, dv;
  if (*flag){ sv = e[i];     dv = e[NEDGES + i]; }
  else      { sv = e[2*i];   dv = e[2*NEDGES + 2*i]; }   // int64 lo words
  sv = sv < 0 ? 0 : (sv > NNODES-1 ? NNODES-1 : sv);
  dv = dv < 0 ? 0 : (dv > NNODES-1 ? NNODES-1 : dv);
  s[i] = sv; d[i] = dv;
}

// ---------------- counting sort by dst (single permutation) ----------------
__global__ void hist_k(const int* __restrict__ d, int* __restrict__ cnt){
  int i = blockIdx.x * 256 + threadIdx.x;
  if (i < NEDGES) atomicAdd(&cnt[d[i]], 1);
}
__global__ __launch_bounds__(256)
void scan_k(const int* __restrict__ cnt, int* __restrict__ rp, int* __restrict__ cur){
  const int SEG = (NNODES + 255) / 256;
  const int t = threadIdx.x;
  const int lo = t * SEG;
  const int hi = (lo + SEG < NNODES) ? lo + SEG : NNODES;
  int s = 0;
  for (int i = lo; i < hi; ++i) s += cnt[i];
  __shared__ int sh[256];
  sh[t] = s; __syncthreads();
  for (int o = 1; o < 256; o <<= 1){
    int v = (t >= o) ? sh[t - o] : 0;
    __syncthreads();
    sh[t] += v;
    __syncthreads();
  }
  int pre = t ? sh[t-1] : 0;
  for (int i = lo; i < hi; ++i){
    rp[i] = pre; cur[i] = pre; pre += cnt[i];
  }
  if (t == 255) rp[NNODES] = sh[255];
}
// ONE permutation: sorted position p gets src id AND original edge id.
__global__ void permute_k(const int* __restrict__ srcN, const int* __restrict__ dstN,
                          int* __restrict__ cur, int* __restrict__ srcS,
                          int* __restrict__ eidx){
  int i = blockIdx.x * 256 + threadIdx.x;
  if (i < NEDGES){
    int d = dstN[i];
    int p = atomicAdd(&cur[d], 1);
    srcS[p] = srcN[i];
    eidx[p] = i;
  }
}
__global__ void fill_dstS(const int* __restrict__ rp, int* __restrict__ dstS){
  int n = blockIdx.x;
  int lo = rp[n], hi = rp[n+1];
  for (int e = lo + threadIdx.x; e < hi; e += 64) dstS[e] = n;
}

// ---------------- casts ----------------
__global__ void cast_bf16_vec(const float4* __restrict__ in, ushort4* __restrict__ out, int n4){
  int i = blockIdx.x * 256 + threadIdx.x;
  if (i < n4){
    float4 v = in[i];
    ushort4 o; o.x = f2bf(v.x); o.y = f2bf(v.y); o.z = f2bf(v.z); o.w = f2bf(v.w);
    out[i] = o;
  }
}
__global__ void transpose_cast(const float* __restrict__ W, uint16_t* __restrict__ WT, int K, int N){
  int k = blockIdx.x * 256 + threadIdx.x;
  int n = blockIdx.y;
  if (k < K) WT[(size_t)n * K + k] = f2bf(W[(size_t)k * N + n]);
}

// ---------------- fused MFMA GEMM (128x128 tile, BK=64, 4 waves) ----------------
// Grid: blockIdx.x = COL tile (fast -> consecutive blocks share the A panel),
//       blockIdx.y = ROW tile.
// AM_NODE: row gm = [xb[gm] | aggb[gm]]  (K = 1024)
// AM_DIR : row-major A0, stride KTOT
// BPQ=1  : B^T row n -> w1t + (n&511)*bstr + (n>>9)*512  (fused P|Q, N=1024)
template<int AMODE, int EPI, int KTOT, int BPQ>
__global__ __launch_bounds__(256, 2)
void gemm_k(const uint16_t* __restrict__ A0, const uint16_t* __restrict__ A1,
            const uint16_t* __restrict__ BT, const float* __restrict__ bias,
            uint16_t* __restrict__ Cb, float* __restrict__ Cf,
            int bstr, int cstr, int m0base, int M, int crowOff)
{
  __shared__ __align__(16) char smem[32768];
  char* As = smem;
  char* Bs = smem + 16384;
  const int t = threadIdx.x;
  const int m0 = m0base + blockIdx.y * 128;
  const int n0 = blockIdx.x * 128;
  const int srow = t >> 3;
  const int c8   = t & 7;
  const int scol = ((c8 ^ (srow & 7)) << 3);
  const int ldst = srow * 128 + c8 * 16;

  const uint16_t* as0[4]; const uint16_t* as1[4];
  #pragma unroll
  for (int i = 0; i < 4; ++i){
    int gm = m0 + srow + 32*i;
    if (gm > M - 1) gm = M - 1;
    if (AMODE == AM_NODE){
      as0[i] = A0 + (size_t)gm * HID;
      as1[i] = A1 + (size_t)gm * HID;
    } else {
      as0[i] = A0 + (size_t)gm * KTOT;
      as1[i] = A0;
    }
  }
  const uint16_t* brow[4];
  #pragma unroll
  for (int i = 0; i < 4; ++i){
    int nr = n0 + srow + 32*i;
    if (BPQ) brow[i] = BT + (size_t)(nr & (HID-1))*bstr + (nr >> 9)*HID;
    else     brow[i] = BT + (size_t)nr*bstr;
  }

  const int lane = t & 63;
  const int wv = t >> 6;
  const int wm = (wv >> 1) * 64;
  const int wn = (wv & 1) * 64;
  const int l15 = lane & 15;
  const int lk16 = (lane >> 4) << 4;
  const int swz = (l15 & 7) << 4;

  f32x4 acc[4][4] = {};

  const int NK = KTOT / 64;
  for (int kk = 0; kk < NK; ++kk){
    const int k0 = kk * 64;
    #pragma unroll
    for (int i = 0; i < 4; ++i){
      const uint16_t* g;
      if (AMODE == AM_NODE){
        g = (k0 < HID) ? as0[i] + (k0 + scol) : as1[i] + (k0 - HID + scol);
      } else {
        g = as0[i] + (k0 + scol);
      }
      gl_lds16(g, As + i*4096 + ldst);
    }
    #pragma unroll
    for (int i = 0; i < 4; ++i)
      gl_lds16(brow[i] + (k0 + scol), Bs + i*4096 + ldst);
    __syncthreads();
    #pragma unroll
    for (int ks = 0; ks < 2; ++ks){
      bf16x8 af[4], bfr[4];
      #pragma unroll
      for (int i = 0; i < 4; ++i){
        const int ar = wm + i*16 + l15;
        af[i] = *(const bf16x8*)(As + ar*128 + ((ks*64 + lk16) ^ swz));
      }
      #pragma unroll
      for (int j = 0; j < 4; ++j){
        const int br = wn + j*16 + l15;
        bfr[j] = *(const bf16x8*)(Bs + br*128 + ((ks*64 + lk16) ^ swz));
      }
      #pragma unroll
      for (int i = 0; i < 4; ++i)
        #pragma unroll
        for (int j = 0; j < 4; ++j)
          acc[i][j] = __builtin_amdgcn_mfma_f32_16x16x32_bf16(af[i], bfr[j], acc[i][j], 0, 0, 0);
    }
    __syncthreads();
  }

  #pragma unroll
  for (int i = 0; i < 4; ++i){
    const int rb = wm + i*16 + ((lane >> 4) << 2);
    #pragma unroll
    for (int j = 0; j < 4; ++j){
      const int gcol = n0 + wn + j*16 + l15;
      const float bv = (EPI == EP_BF16L) ? 0.f : bias[gcol];
      #pragma unroll
      for (int r = 0; r < 4; ++r){
        const int grow = m0 + rb + r;
        if (grow < M){
          float v = acc[i][j][r] + bv;
          if (EPI == EP_BF16){
            Cb[(size_t)(grow - crowOff) * cstr + gcol] = f2bf(mishf(v));
          } else if (EPI == EP_BF16L){
            Cb[(size_t)(grow - crowOff) * cstr + gcol] = f2bf(v);
          } else {
            Cf[(size_t)grow * cstr + gcol] = v;
          }
        }
      }
    }
  }
}

// ---------------- EH: h = mish(ea@W1c + P[src] + Q[dst] + b1) ----------------
// 256 threads = 4 waves; block = 32 edges x 512 cols; wave wv owns cols [wv*128, +128).
// K = 64 (2 MFMA k-steps), acc[2][8]. A-frags direct bf16x8 loads from eab.
// Epilogue: stage acc quarter-tile in wave-private LDS (XOR-bit6 swizzle), read back
// row-linear -> P/Q/h coalesced. PQb layout: [n][1024], P = 0..511, Q = 512..1023.
__global__ __launch_bounds__(256, 4)
void eh_k(const uint16_t* __restrict__ eab, const uint16_t* __restrict__ PQb,
          const int* __restrict__ idx,
          const uint16_t* __restrict__ w1t, const float* __restrict__ b1,
          uint16_t* __restrict__ hb, int m0base, int crowOff)
{
  __shared__ __align__(16) char smem[32768];   // 4 waves x 8KB (16 rows x 512B)
  const int t = threadIdx.x;
  const int m0 = m0base + blockIdx.x * 32;
  const int lane = t & 63;
  const int wv = t >> 6;
  const int l15 = lane & 15;
  const int lg = lane >> 4;                    // 0..3
  const int* srcS = idx;
  const int* dstS = idx + NEDGES;
  const int* eidx = idx + 2*NEDGES;

  int eidxr[2];
  #pragma unroll
  for (int fr = 0; fr < 2; ++fr) eidxr[fr] = eidx[m0 + fr*16 + l15];

  f32x4 acc[2][8] = {};

  #pragma unroll
  for (int ks = 0; ks < 2; ++ks){
    bf16x8 bF[8];
    #pragma unroll
    for (int fc = 0; fc < 8; ++fc){
      int n = wv*128 + fc*16 + l15;
      bF[fc] = *(const bf16x8*)(w1t + (size_t)n*KFEAT + 2*HID + ks*32 + lg*8);
    }
    #pragma unroll
    for (int fr = 0; fr < 2; ++fr){
      bf16x8 av = *(const bf16x8*)(eab + (size_t)eidxr[fr]*EDIM + ks*32 + lg*8);
      #pragma unroll
      for (int fc = 0; fc < 8; ++fc)
        acc[fr][fc] = __builtin_amdgcn_mfma_f32_16x16x32_bf16(av, bF[fc], acc[fr][fc], 0, 0, 0);
    }
  }

  // epilogue: per fr quarter (16 rows x 128 cols), wave-private slab
  char* slab = smem + wv*8192;
  const float4 b1v0 = *(const float4*)(b1 + wv*128 + l15*4);
  const float4 b1v1 = *(const float4*)(b1 + wv*128 + 64 + l15*4);
  #pragma unroll
  for (int fr = 0; fr < 2; ++fr){
    #pragma unroll
    for (int fc = 0; fc < 8; ++fc){
      #pragma unroll
      for (int r = 0; r < 4; ++r){
        int row = lg*4 + r;                    // row>>2 == lg
        int cb = ((fc*16 + l15)*4) ^ ((lg & 1) << 6);
        *(float*)(slab + row*512 + cb) = acc[fr][fc][r];
      }
    }
    asm volatile("s_waitcnt lgkmcnt(0)" ::: "memory");
    __builtin_amdgcn_sched_barrier(0);
    #pragma unroll
    for (int i = 0; i < 4; ++i){
      int row = i*4 + lg;                      // row>>2 == i
      int grow = m0 + fr*16 + row;
      int s = srcS[grow];
      int d = dstS[grow];
      float4 v0 = *(const float4*)(slab + row*512 + ((l15*16) ^ ((i & 1) << 6)));
      float4 v1 = *(const float4*)(slab + row*512 + ((256 + l15*16) ^ ((i & 1) << 6)));
      ushort4 p0 = *(const ushort4*)(PQb + (size_t)s*1024 + wv*128 + l15*4);
      ushort4 p1 = *(const ushort4*)(PQb + (size_t)s*1024 + wv*128 + 64 + l15*4);
      ushort4 q0 = *(const ushort4*)(PQb + (size_t)d*1024 + 512 + wv*128 + l15*4);
      ushort4 q1 = *(const ushort4*)(PQb + (size_t)d*1024 + 512 + wv*128 + 64 + l15*4);
      ushort4 h0, h1;
      h0.x = f2bf(mishf(v0.x + bf2f(p0.x) + bf2f(q0.x) + b1v0.x));
      h0.y = f2bf(mishf(v0.y + bf2f(p0.y) + bf2f(q0.y) + b1v0.y));
      h0.z = f2bf(mishf(v0.z + bf2f(p0.z) + bf2f(q0.z) + b1v0.z));
      h0.w = f2bf(mishf(v0.w + bf2f(p0.w) + bf2f(q0.w) + b1v0.w));
      h1.x = f2bf(mishf(v1.x + bf2f(p1.x) + bf2f(q1.x) + b1v1.x));
      h1.y = f2bf(mishf(v1.y + bf2f(p1.y) + bf2f(q1.y) + b1v1.y));
      h1.z = f2bf(mishf(v1.z + bf2f(p1.z) + bf2f(q1.z) + b1v1.z));
      h1.w = f2bf(mishf(v1.w + bf2f(p1.w) + bf2f(q1.w) + b1v1.w));
      size_t hrow = (size_t)(grow - crowOff) * HID + wv*128;
      *(ushort4*)(hb + hrow + l15*4) = h0;
      *(ushort4*)(hb + hrow + 64 + l15*4) = h1;
    }
    asm volatile("s_waitcnt lgkmcnt(0)" ::: "memory");
    __builtin_amdgcn_sched_barrier(0);
  }
}

// ---------------- CSR gather-reduce (no atomics) ----------------
__global__ __launch_bounds__(128)
void gather_agg(const uint16_t* __restrict__ msg, const int* __restrict__ rp,
                float* __restrict__ agg, int e0, int e1){
  const int n = blockIdx.x;
  int lo = rp[n], hi = rp[n+1];
  if (lo < e0) lo = e0;
  if (hi > e1) hi = e1;
  if (lo >= hi) return;
  const int t = threadIdx.x;
  float4 a = {0.f, 0.f, 0.f, 0.f};
  for (int e = lo; e < hi; ++e){
    ushort4 m = ((const ushort4*)(msg + (size_t)(e - e0) * HID))[t];
    a.x += bf2f(m.x); a.y += bf2f(m.y); a.z += bf2f(m.z); a.w += bf2f(m.w);
  }
  float4* ap = ((float4*)(agg + (size_t)n * HID)) + t;
  float4 c = *ap;
  c.x += a.x; c.y += a.y; c.z += a.z; c.w += a.w;
  *ap = c;
}

// ---------------- residual + LayerNorm ----------------
__global__ __launch_bounds__(128)
void resid_ln(const float* __restrict__ x, const float* __restrict__ ob,
              const float* __restrict__ gamma, const float* __restrict__ beta,
              float* __restrict__ y){
  const int row = blockIdx.x;
  const int t = threadIdx.x;
  const float4 xv = ((const float4*)(x + (size_t)row * HID))[t];
  const float4 ov = ((const float4*)(ob + (size_t)row * HID))[t];
  float4 s4;
  s4.x = xv.x + ov.x; s4.y = xv.y + ov.y; s4.z = xv.z + ov.z; s4.w = xv.w + ov.w;
  float s = s4.x + s4.y + s4.z + s4.w;
  float q = s4.x*s4.x + s4.y*s4.y + s4.z*s4.z + s4.w*s4.w;
  #pragma unroll
  for (int o = 32; o; o >>= 1){
    s += __shfl_xor(s, o, 64);
    q += __shfl_xor(q, o, 64);
  }
  __shared__ float ss[2], qq[2];
  if ((t & 63) == 0){ ss[t >> 6] = s; qq[t >> 6] = q; }
  __syncthreads();
  const float S = ss[0] + ss[1], Q = qq[0] + qq[1];
  const float mu = S * (1.0f / HID);
  const float var = Q * (1.0f / HID) - mu * mu;
  const float inv = rsqrtf(var + 1e-5f);
  const float4 g = ((const float4*)gamma)[t];
  const float4 b = ((const float4*)beta)[t];
  float4 o;
  o.x = (s4.x - mu) * inv * g.x + b.x;
  o.y = (s4.y - mu) * inv * g.y + b.y;
  o.z = (s4.z - mu) * inv * g.z + b.z;
  o.w = (s4.w - mu) * inv * g.w + b.w;
  ((float4*)(y + (size_t)row * HID))[t] = o;
}

extern "C" void kernel_launch(void* const* d_in, const int* in_sizes, int n_in,
                              void* d_out, int out_size, void* d_ws, size_t ws_size,
                              hipStream_t stream)
{
  const float* x    = (const float*)d_in[0];
  const int*   ei   = (const int*)d_in[1];
  const float* ea   = (const float*)d_in[2];
  const float* W1   = (const float*)d_in[3];
  const float* b1   = (const float*)d_in[4];
  const float* W2   = (const float*)d_in[5];
  const float* b2   = (const float*)d_in[6];
  const float* W3   = (const float*)d_in[7];
  const float* b3   = (const float*)d_in[8];
  const float* W4   = (const float*)d_in[9];
  const float* b4   = (const float*)d_in[10];
  const float* gmm  = (const float*)d_in[11];
  const float* bet  = (const float*)d_in[12];
  float* out = (float*)d_out;

  uint8_t* w = (uint8_t*)d_ws;
  size_t off = 0;
  auto alloc = [&](size_t bytes) -> void* {
    void* p = w + off;
    off += (bytes + 255) & ~(size_t)255;
    return p;
  };
  uint16_t* xb   = (uint16_t*)alloc((size_t)NNODES*HID*2);
  uint16_t* w1t  = (uint16_t*)alloc((size_t)HID*KFEAT*2);
  uint16_t* w2t  = (uint16_t*)alloc((size_t)HID*HID*2);
  uint16_t* w3t  = (uint16_t*)alloc((size_t)HID*1024*2);
  uint16_t* w4t  = (uint16_t*)alloc((size_t)HID*HID*2);
  uint16_t* PQb  = (uint16_t*)alloc((size_t)NNODES*1024*2);   // [n][1024]: P|Q
  float*    agg  = (float*)alloc((size_t)NNODES*HID*4);
  uint16_t* aggb = (uint16_t*)alloc((size_t)NNODES*HID*2);
  uint16_t* ub   = (uint16_t*)alloc((size_t)NNODES*HID*2);
  float*    outf = (float*)alloc((size_t)NNODES*HID*4);
  int*      srcN = (int*)alloc((size_t)NEDGES*4);
  int*      dstN = (int*)alloc((size_t)NEDGES*4);
  int*      idxS = (int*)alloc((size_t)NEDGES*4*3);  // [srcS | dstS | eidx]
  int*      cnt  = (int*)alloc((size_t)NNODES*4);
  int*      rp   = (int*)alloc((size_t)(NNODES+1)*4);
  int*      cur  = (int*)alloc((size_t)NNODES*4);
  int*      flag = (int*)alloc(256);
  int*      srcS = idxS;
  int*      dstS = idxS + NEDGES;
  int*      eidx = idxS + 2*NEDGES;

  // eab (bf16 edge_attr, 40.96 MB) aliases outf (40.96 MB): eab is dead before
  // GEMM4 writes outf (stream-ordered), so no extra workspace is consumed.
  uint16_t* eab = (uint16_t*)outf;

  size_t remain = (ws_size > off) ? ws_size - off : 0;
  size_t maxChunk = remain / ((size_t)HID*2*2);    // hb + msgb
  long long chunkE = (long long)(maxChunk & ~(size_t)127);
  if (chunkE > NEDGES) chunkE = NEDGES;
  if (chunkE < 128) chunkE = 128;
  uint16_t* hb   = (uint16_t*)alloc((size_t)chunkE*HID*2);
  uint16_t* msgb = (uint16_t*)alloc((size_t)chunkE*HID*2);

  hipMemsetAsync(agg, 0, (size_t)NNODES*HID*4, stream);
  hipMemsetAsync(cnt, 0, (size_t)NNODES*4, stream);
  hipMemsetAsync(flag, 0, 4, stream);

  detect_idx<<<64, 256, 0, stream>>>(ei, flag);
  norm_idx<<<(NEDGES+255)/256, 256, 0, stream>>>(ei, flag, srcN, dstN);
  hist_k<<<(NEDGES+255)/256, 256, 0, stream>>>(dstN, cnt);
  scan_k<<<1, 256, 0, stream>>>(cnt, rp, cur);
  permute_k<<<(NEDGES+255)/256, 256, 0, stream>>>(srcN, dstN, cur, srcS, eidx);
  fill_dstS<<<NNODES, 64, 0, stream>>>(rp, dstS);

  cast_bf16_vec<<<(NNODES*HID/4+255)/256, 256, 0, stream>>>((const float4*)x, (ushort4*)xb, NNODES*HID/4);
  cast_bf16_vec<<<(NEDGES*EDIM/4+255)/256, 256, 0, stream>>>((const float4*)ea, (ushort4*)eab, NEDGES*EDIM/4);

  transpose_cast<<<dim3((KFEAT+255)/256, HID), 256, 0, stream>>>(W1, w1t, KFEAT, HID);
  transpose_cast<<<dim3((HID+255)/256,   HID), 256, 0, stream>>>(W2, w2t, HID, HID);
  transpose_cast<<<dim3((1024+255)/256,  HID), 256, 0, stream>>>(W3, w3t, 1024, HID);
  transpose_cast<<<dim3((HID+255)/256,   HID), 256, 0, stream>>>(W4, w4t, HID, HID);

  // Fused P|Q = x @ [W1a | W1b]  (N=1024, bf16 output, no bias/act)
  // grid: col tiles fast -> xb A-panel fetched once
  dim3 gpq(1024/128, (NNODES+127)/128);
  gemm_k<AM_DIR, EP_BF16L, HID, 1><<<gpq, 256, 0, stream>>>(
      xb, nullptr, w1t, b1, PQb, nullptr, KFEAT, 1024, 0, NNODES, 0);

  for (long long e0 = 0; e0 < NEDGES; e0 += chunkE){
    int ce = (int)((NEDGES - e0 < chunkE) ? (NEDGES - e0) : chunkE);
    // EH: h = mish(ea@W1c + P[src] + Q[dst] + b1) -> hb (chunk-local)
    eh_k<<<(ce+31)/32, 256, 0, stream>>>(eab, PQb, idxS, w1t, b1, hb, (int)e0, (int)e0);
    // GEMM2: hb @ W2 + mish -> msgb (bf16, sorted edge order); col-fast grid
    dim3 g2(HID/128, (ce+127)/128);
    gemm_k<AM_DIR, EP_BF16, HID, 0><<<g2, 256, 0, stream>>>(
        hb, nullptr, w2t, b2, msgb, nullptr, HID, HID, 0, ce, 0);
    // CSR gather-reduce into agg (fp32, no atomics)
    gather_agg<<<NNODES, 128, 0, stream>>>(msgb, rp, agg, (int)e0, (int)(e0+ce));
  }

  cast_bf16_vec<<<(NNODES*HID/4+255)/256, 256, 0, stream>>>((const float4*)agg, (ushort4*)aggb, NNODES*HID/4);

  dim3 g3(HID/128, (NNODES+127)/128);
  gemm_k<AM_NODE, EP_BF16, 1024, 0><<<g3, 256, 0, stream>>>(
      xb, aggb, w3t, b3, ub, nullptr, 1024, HID, 0, NNODES, 0);
  gemm_k<AM_DIR, EP_F32, HID, 0><<<g3, 256, 0, stream>>>(
      ub, nullptr, w4t, b4, nullptr, outf, HID, HID, 0, NNODES, 0);

  resid_ln<<<NNODES, 128, 0, stream>>>(x, outf, gmm, bet, out);
}

// Round 11
// 912.911 us; speedup vs baseline: 1.1369x; 1.0283x over previous
//
#include <hip/hip_runtime.h>
#include <cstdint>
#include <cstddef>

#define NNODES 20000
#define NEDGES 320000
#define HID 512
#define EDIM 64
#define KFEAT (2*HID + EDIM)   // 1088

typedef __bf16 bf16x8 __attribute__((ext_vector_type(8)));
typedef short short8 __attribute__((ext_vector_type(8)));
typedef float f32x4 __attribute__((ext_vector_type(4)));

#define AM_NODE 1
#define AM_DIR  2
#define EP_BF16    0   // +bias, mish, bf16 store
#define EP_F32     2   // +bias, raw f32 store
#define EP_BF16L   3   // no bias, no mish, bf16 store
#define EP_RAW     5   // raw f2bf(acc) store (bias+mish deferred to consumer)

__device__ __forceinline__ uint16_t f2bf(float f){
  uint32_t u = __float_as_uint(f);
  u += 0x7FFFu + ((u >> 16) & 1u);
  return (uint16_t)(u >> 16);
}
__device__ __forceinline__ float bf2f(uint16_t h){
  return __uint_as_float((uint32_t)h << 16);
}
// mish(x) = x * tanh(softplus(x)) = x * (e^2+2e)/(e^2+2e+2), e = exp(x)
__device__ __forceinline__ float mishf(float v){
  float e = __expf(fminf(v, 18.f));
  float n = e * (e + 2.f);
  return v * __fdividef(n, n + 2.f);
}
__device__ __forceinline__ void gl_lds16(const void* g, void* l){
  __builtin_amdgcn_global_load_lds(
      (const __attribute__((address_space(1))) uint32_t*)g,
      (__attribute__((address_space(3))) uint32_t*)l, 16, 0, 0);
}

// ---------------- index dtype detect / normalize ----------------
__global__ void detect_idx(const int* __restrict__ e, int* __restrict__ flag){
  int i = blockIdx.x * 256 + threadIdx.x;   // probe first 16384 pairs
  if (e[2*i + 1] != 0) atomicOr(flag, 1);   // flag=1 -> int32 layout
}
__global__ void norm_idx(const int* __restrict__ e, const int* __restrict__ flag,
                         int* __restrict__ s, int* __restrict__ d){
  int i = blockIdx.x * 256 + threadIdx.x;
  if (i >= NEDGES) return;
  int sv, dv;
  if (*flag){ sv = e[i];     dv = e[NEDGES + i]; }
  else      { sv = e[2*i];   dv = e[2*NEDGES + 2*i]; }   // int64 lo words
  sv = sv < 0 ? 0 : (sv > NNODES-1 ? NNODES-1 : sv);
  dv = dv < 0 ? 0 : (dv > NNODES-1 ? NNODES-1 : dv);
  s[i] = sv; d[i] = dv;
}

// ---------------- counting sort by dst (single permutation) ----------------
__global__ void hist_k(const int* __restrict__ d, int* __restrict__ cnt){
  int i = blockIdx.x * 256 + threadIdx.x;
  if (i < NEDGES) atomicAdd(&cnt[d[i]], 1);
}
__global__ __launch_bounds__(256)
void scan_k(const int* __restrict__ cnt, int* __restrict__ rp, int* __restrict__ cur){
  const int SEG = (NNODES + 255) / 256;
  const int t = threadIdx.x;
  const int lo = t * SEG;
  const int hi = (lo + SEG < NNODES) ? lo + SEG : NNODES;
  int s = 0;
  for (int i = lo; i < hi; ++i) s += cnt[i];
  __shared__ int sh[256];
  sh[t] = s; __syncthreads();
  for (int o = 1; o < 256; o <<= 1){
    int v = (t >= o) ? sh[t - o] : 0;
    __syncthreads();
    sh[t] += v;
    __syncthreads();
  }
  int pre = t ? sh[t-1] : 0;
  for (int i = lo; i < hi; ++i){
    rp[i] = pre; cur[i] = pre; pre += cnt[i];
  }
  if (t == 255) rp[NNODES] = sh[255];
}
// ONE permutation: sorted position p gets src id AND original edge id.
__global__ void permute_k(const int* __restrict__ srcN, const int* __restrict__ dstN,
                          int* __restrict__ cur, int* __restrict__ srcS,
                          int* __restrict__ eidx){
  int i = blockIdx.x * 256 + threadIdx.x;
  if (i < NEDGES){
    int d = dstN[i];
    int p = atomicAdd(&cur[d], 1);
    srcS[p] = srcN[i];
    eidx[p] = i;
  }
}
__global__ void fill_dstS(const int* __restrict__ rp, int* __restrict__ dstS){
  int n = blockIdx.x;
  int lo = rp[n], hi = rp[n+1];
  for (int e = lo + threadIdx.x; e < hi; e += 64) dstS[e] = n;
}

// ---------------- casts ----------------
__global__ void cast_bf16_vec(const float4* __restrict__ in, ushort4* __restrict__ out, int n4){
  int i = blockIdx.x * 256 + threadIdx.x;
  if (i < n4){
    float4 v = in[i];
    ushort4 o; o.x = f2bf(v.x); o.y = f2bf(v.y); o.z = f2bf(v.z); o.w = f2bf(v.w);
    out[i] = o;
  }
}
__global__ void transpose_cast(const float* __restrict__ W, uint16_t* __restrict__ WT, int K, int N){
  int k = blockIdx.x * 256 + threadIdx.x;
  int n = blockIdx.y;
  if (k < K) WT[(size_t)n * K + k] = f2bf(W[(size_t)k * N + n]);
}

// ---------------- fused MFMA GEMM (128x128 tile, BK=64, 4 waves) ----------------
// Block remap: when nty%8==0, group row panels per XCD (flat%8 == XCD round-robin):
//   xcd = flat&7, i = flat>>3, by = xcd*(nty/8) + i/ntx, bx = i%ntx
// so all col-tiles of one A panel fill the SAME per-XCD L2. Else identity (col-fast).
// AM_NODE: row gm = [xb[gm] | aggb[gm]]  (K = 1024)
// AM_DIR : row-major A0, stride KTOT
// BPQ=1  : B^T row n -> w1t + (n&511)*bstr + (n>>9)*512  (fused P|Q, N=1024)
template<int AMODE, int EPI, int KTOT, int BPQ>
__global__ __launch_bounds__(256, 2)
void gemm_k(const uint16_t* __restrict__ A0, const uint16_t* __restrict__ A1,
            const uint16_t* __restrict__ BT, const float* __restrict__ bias,
            uint16_t* __restrict__ Cb, float* __restrict__ Cf,
            int bstr, int cstr, int m0base, int M, int crowOff)
{
  __shared__ __align__(16) char smem[32768];
  char* As = smem;
  char* Bs = smem + 16384;
  const int t = threadIdx.x;
  const int ntx = gridDim.x, nty = gridDim.y;
  int bx = blockIdx.x, by = blockIdx.y;
  if ((nty & 7) == 0){
    int flat = by * ntx + bx;
    int xcd = flat & 7;
    int i = flat >> 3;
    by = xcd * (nty >> 3) + i / ntx;
    bx = i % ntx;
  }
  const int m0 = m0base + by * 128;
  const int n0 = bx * 128;
  const int srow = t >> 3;
  const int c8   = t & 7;
  const int scol = ((c8 ^ (srow & 7)) << 3);
  const int ldst = srow * 128 + c8 * 16;

  const uint16_t* as0[4]; const uint16_t* as1[4];
  #pragma unroll
  for (int i = 0; i < 4; ++i){
    int gm = m0 + srow + 32*i;
    if (gm > M - 1) gm = M - 1;
    if (AMODE == AM_NODE){
      as0[i] = A0 + (size_t)gm * HID;
      as1[i] = A1 + (size_t)gm * HID;
    } else {
      as0[i] = A0 + (size_t)gm * KTOT;
      as1[i] = A0;
    }
  }
  const uint16_t* brow[4];
  #pragma unroll
  for (int i = 0; i < 4; ++i){
    int nr = n0 + srow + 32*i;
    if (BPQ) brow[i] = BT + (size_t)(nr & (HID-1))*bstr + (nr >> 9)*HID;
    else     brow[i] = BT + (size_t)nr*bstr;
  }

  const int lane = t & 63;
  const int wv = t >> 6;
  const int wm = (wv >> 1) * 64;
  const int wn = (wv & 1) * 64;
  const int l15 = lane & 15;
  const int lk16 = (lane >> 4) << 4;
  const int swz = (l15 & 7) << 4;

  f32x4 acc[4][4] = {};

  const int NK = KTOT / 64;
  for (int kk = 0; kk < NK; ++kk){
    const int k0 = kk * 64;
    #pragma unroll
    for (int i = 0; i < 4; ++i){
      const uint16_t* g;
      if (AMODE == AM_NODE){
        g = (k0 < HID) ? as0[i] + (k0 + scol) : as1[i] + (k0 - HID + scol);
      } else {
        g = as0[i] + (k0 + scol);
      }
      gl_lds16(g, As + i*4096 + ldst);
    }
    #pragma unroll
    for (int i = 0; i < 4; ++i)
      gl_lds16(brow[i] + (k0 + scol), Bs + i*4096 + ldst);
    __syncthreads();
    #pragma unroll
    for (int ks = 0; ks < 2; ++ks){
      bf16x8 af[4], bfr[4];
      #pragma unroll
      for (int i = 0; i < 4; ++i){
        const int ar = wm + i*16 + l15;
        af[i] = *(const bf16x8*)(As + ar*128 + ((ks*64 + lk16) ^ swz));
      }
      #pragma unroll
      for (int j = 0; j < 4; ++j){
        const int br = wn + j*16 + l15;
        bfr[j] = *(const bf16x8*)(Bs + br*128 + ((ks*64 + lk16) ^ swz));
      }
      #pragma unroll
      for (int i = 0; i < 4; ++i)
        #pragma unroll
        for (int j = 0; j < 4; ++j)
          acc[i][j] = __builtin_amdgcn_mfma_f32_16x16x32_bf16(af[i], bfr[j], acc[i][j], 0, 0, 0);
    }
    __syncthreads();
  }

  #pragma unroll
  for (int i = 0; i < 4; ++i){
    const int rb = wm + i*16 + ((lane >> 4) << 2);
    #pragma unroll
    for (int j = 0; j < 4; ++j){
      const int gcol = n0 + wn + j*16 + l15;
      const float bv = (EPI == EP_BF16L || EPI == EP_RAW) ? 0.f : bias[gcol];
      #pragma unroll
      for (int r = 0; r < 4; ++r){
        const int grow = m0 + rb + r;
        if (grow < M){
          float v = acc[i][j][r] + bv;
          if (EPI == EP_BF16){
            Cb[(size_t)(grow - crowOff) * cstr + gcol] = f2bf(mishf(v));
          } else if (EPI == EP_BF16L || EPI == EP_RAW){
            Cb[(size_t)(grow - crowOff) * cstr + gcol] = f2bf(v);
          } else {
            Cf[(size_t)grow * cstr + gcol] = v;
          }
        }
      }
    }
  }
}

// ---------------- EH: h = mish(ea@W1c + P[src] + Q[dst] + b1) ----------------
// 256 threads = 4 waves; block = 32 edges x 512 cols; wave wv owns cols [wv*128, +128).
// K = 64 (2 MFMA k-steps), acc[2][8]. A-frags direct bf16x8 loads from eab.
// Epilogue: stage acc quarter-tile in wave-private LDS (XOR-bit6 swizzle), read back
// row-linear -> P/Q/h coalesced. PQb layout: [n][1024], P = 0..511, Q = 512..1023.
__global__ __launch_bounds__(256, 4)
void eh_k(const uint16_t* __restrict__ eab, const uint16_t* __restrict__ PQb,
          const int* __restrict__ idx,
          const uint16_t* __restrict__ w1t, const float* __restrict__ b1,
          uint16_t* __restrict__ hb, int m0base, int crowOff)
{
  __shared__ __align__(16) char smem[32768];   // 4 waves x 8KB (16 rows x 512B)
  const int t = threadIdx.x;
  const int m0 = m0base + blockIdx.x * 32;
  const int lane = t & 63;
  const int wv = t >> 6;
  const int l15 = lane & 15;
  const int lg = lane >> 4;                    // 0..3
  const int* srcS = idx;
  const int* dstS = idx + NEDGES;
  const int* eidx = idx + 2*NEDGES;

  int eidxr[2];
  #pragma unroll
  for (int fr = 0; fr < 2; ++fr) eidxr[fr] = eidx[m0 + fr*16 + l15];

  f32x4 acc[2][8] = {};

  #pragma unroll
  for (int ks = 0; ks < 2; ++ks){
    bf16x8 bF[8];
    #pragma unroll
    for (int fc = 0; fc < 8; ++fc){
      int n = wv*128 + fc*16 + l15;
      bF[fc] = *(const bf16x8*)(w1t + (size_t)n*KFEAT + 2*HID + ks*32 + lg*8);
    }
    #pragma unroll
    for (int fr = 0; fr < 2; ++fr){
      bf16x8 av = *(const bf16x8*)(eab + (size_t)eidxr[fr]*EDIM + ks*32 + lg*8);
      #pragma unroll
      for (int fc = 0; fc < 8; ++fc)
        acc[fr][fc] = __builtin_amdgcn_mfma_f32_16x16x32_bf16(av, bF[fc], acc[fr][fc], 0, 0, 0);
    }
  }

  // epilogue: per fr quarter (16 rows x 128 cols), wave-private slab
  char* slab = smem + wv*8192;
  const float4 b1v0 = *(const float4*)(b1 + wv*128 + l15*4);
  const float4 b1v1 = *(const float4*)(b1 + wv*128 + 64 + l15*4);
  #pragma unroll
  for (int fr = 0; fr < 2; ++fr){
    #pragma unroll
    for (int fc = 0; fc < 8; ++fc){
      #pragma unroll
      for (int r = 0; r < 4; ++r){
        int row = lg*4 + r;                    // row>>2 == lg
        int cb = ((fc*16 + l15)*4) ^ ((lg & 1) << 6);
        *(float*)(slab + row*512 + cb) = acc[fr][fc][r];
      }
    }
    asm volatile("s_waitcnt lgkmcnt(0)" ::: "memory");
    __builtin_amdgcn_sched_barrier(0);
    #pragma unroll
    for (int i = 0; i < 4; ++i){
      int row = i*4 + lg;                      // row>>2 == i
      int grow = m0 + fr*16 + row;
      int s = srcS[grow];
      int d = dstS[grow];
      float4 v0 = *(const float4*)(slab + row*512 + ((l15*16) ^ ((i & 1) << 6)));
      float4 v1 = *(const float4*)(slab + row*512 + ((256 + l15*16) ^ ((i & 1) << 6)));
      ushort4 p0 = *(const ushort4*)(PQb + (size_t)s*1024 + wv*128 + l15*4);
      ushort4 p1 = *(const ushort4*)(PQb + (size_t)s*1024 + wv*128 + 64 + l15*4);
      ushort4 q0 = *(const ushort4*)(PQb + (size_t)d*1024 + 512 + wv*128 + l15*4);
      ushort4 q1 = *(const ushort4*)(PQb + (size_t)d*1024 + 512 + wv*128 + 64 + l15*4);
      ushort4 h0, h1;
      h0.x = f2bf(mishf(v0.x + bf2f(p0.x) + bf2f(q0.x) + b1v0.x));
      h0.y = f2bf(mishf(v0.y + bf2f(p0.y) + bf2f(q0.y) + b1v0.y));
      h0.z = f2bf(mishf(v0.z + bf2f(p0.z) + bf2f(q0.z) + b1v0.z));
      h0.w = f2bf(mishf(v0.w + bf2f(p0.w) + bf2f(q0.w) + b1v0.w));
      h1.x = f2bf(mishf(v1.x + bf2f(p1.x) + bf2f(q1.x) + b1v1.x));
      h1.y = f2bf(mishf(v1.y + bf2f(p1.y) + bf2f(q1.y) + b1v1.y));
      h1.z = f2bf(mishf(v1.z + bf2f(p1.z) + bf2f(q1.z) + b1v1.z));
      h1.w = f2bf(mishf(v1.w + bf2f(p1.w) + bf2f(q1.w) + b1v1.w));
      size_t hrow = (size_t)(grow - crowOff) * HID + wv*128;
      *(ushort4*)(hb + hrow + l15*4) = h0;
      *(ushort4*)(hb + hrow + 64 + l15*4) = h1;
    }
    asm volatile("s_waitcnt lgkmcnt(0)" ::: "memory");
    __builtin_amdgcn_sched_barrier(0);
  }
}

// ---------------- CSR gather-reduce with deferred bias+mish (no atomics) --------
__global__ __launch_bounds__(128)
void gather_agg(const uint16_t* __restrict__ msg, const int* __restrict__ rp,
                const float* __restrict__ b2, float* __restrict__ agg,
                int e0, int e1){
  const int n = blockIdx.x;
  int lo = rp[n], hi = rp[n+1];
  if (lo < e0) lo = e0;
  if (hi > e1) hi = e1;
  if (lo >= hi) return;
  const int t = threadIdx.x;
  const float4 bv = ((const float4*)b2)[t];
  float4 a = {0.f, 0.f, 0.f, 0.f};
  for (int e = lo; e < hi; ++e){
    ushort4 m = ((const ushort4*)(msg + (size_t)(e - e0) * HID))[t];
    a.x += mishf(bf2f(m.x) + bv.x);
    a.y += mishf(bf2f(m.y) + bv.y);
    a.z += mishf(bf2f(m.z) + bv.z);
    a.w += mishf(bf2f(m.w) + bv.w);
  }
  float4* ap = ((float4*)(agg + (size_t)n * HID)) + t;
  float4 c = *ap;
  c.x += a.x; c.y += a.y; c.z += a.z; c.w += a.w;
  *ap = c;
}

// ---------------- residual + LayerNorm ----------------
__global__ __launch_bounds__(128)
void resid_ln(const float* __restrict__ x, const float* __restrict__ ob,
              const float* __restrict__ gamma, const float* __restrict__ beta,
              float* __restrict__ y){
  const int row = blockIdx.x;
  const int t = threadIdx.x;
  const float4 xv = ((const float4*)(x + (size_t)row * HID))[t];
  const float4 ov = ((const float4*)(ob + (size_t)row * HID))[t];
  float4 s4;
  s4.x = xv.x + ov.x; s4.y = xv.y + ov.y; s4.z = xv.z + ov.z; s4.w = xv.w + ov.w;
  float s = s4.x + s4.y + s4.z + s4.w;
  float q = s4.x*s4.x + s4.y*s4.y + s4.z*s4.z + s4.w*s4.w;
  #pragma unroll
  for (int o = 32; o; o >>= 1){
    s += __shfl_xor(s, o, 64);
    q += __shfl_xor(q, o, 64);
  }
  __shared__ float ss[2], qq[2];
  if ((t & 63) == 0){ ss[t >> 6] = s; qq[t >> 6] = q; }
  __syncthreads();
  const float S = ss[0] + ss[1], Q = qq[0] + qq[1];
  const float mu = S * (1.0f / HID);
  const float var = Q * (1.0f / HID) - mu * mu;
  const float inv = rsqrtf(var + 1e-5f);
  const float4 g = ((const float4*)gamma)[t];
  const float4 b = ((const float4*)beta)[t];
  float4 o;
  o.x = (s4.x - mu) * inv * g.x + b.x;
  o.y = (s4.y - mu) * inv * g.y + b.y;
  o.z = (s4.z - mu) * inv * g.z + b.z;
  o.w = (s4.w - mu) * inv * g.w + b.w;
  ((float4*)(y + (size_t)row * HID))[t] = o;
}

extern "C" void kernel_launch(void* const* d_in, const int* in_sizes, int n_in,
                              void* d_out, int out_size, void* d_ws, size_t ws_size,
                              hipStream_t stream)
{
  const float* x    = (const float*)d_in[0];
  const int*   ei   = (const int*)d_in[1];
  const float* ea   = (const float*)d_in[2];
  const float* W1   = (const float*)d_in[3];
  const float* b1   = (const float*)d_in[4];
  const float* W2   = (const float*)d_in[5];
  const float* b2   = (const float*)d_in[6];
  const float* W3   = (const float*)d_in[7];
  const float* b3   = (const float*)d_in[8];
  const float* W4   = (const float*)d_in[9];
  const float* b4   = (const float*)d_in[10];
  const float* gmm  = (const float*)d_in[11];
  const float* bet  = (const float*)d_in[12];
  float* out = (float*)d_out;

  uint8_t* w = (uint8_t*)d_ws;
  size_t off = 0;
  auto alloc = [&](size_t bytes) -> void* {
    void* p = w + off;
    off += (bytes + 255) & ~(size_t)255;
    return p;
  };
  uint16_t* xb   = (uint16_t*)alloc((size_t)NNODES*HID*2);
  uint16_t* w1t  = (uint16_t*)alloc((size_t)HID*KFEAT*2);
  uint16_t* w2t  = (uint16_t*)alloc((size_t)HID*HID*2);
  uint16_t* w3t  = (uint16_t*)alloc((size_t)HID*1024*2);
  uint16_t* w4t  = (uint16_t*)alloc((size_t)HID*HID*2);
  uint16_t* PQb  = (uint16_t*)alloc((size_t)NNODES*1024*2);   // [n][1024]: P|Q
  float*    agg  = (float*)alloc((size_t)NNODES*HID*4);
  uint16_t* aggb = (uint16_t*)alloc((size_t)NNODES*HID*2);
  uint16_t* ub   = (uint16_t*)alloc((size_t)NNODES*HID*2);
  float*    outf = (float*)alloc((size_t)NNODES*HID*4);
  int*      srcN = (int*)alloc((size_t)NEDGES*4);
  int*      dstN = (int*)alloc((size_t)NEDGES*4);
  int*      idxS = (int*)alloc((size_t)NEDGES*4*3);  // [srcS | dstS | eidx]
  int*      cnt  = (int*)alloc((size_t)NNODES*4);
  int*      rp   = (int*)alloc((size_t)(NNODES+1)*4);
  int*      cur  = (int*)alloc((size_t)NNODES*4);
  int*      flag = (int*)alloc(256);
  int*      srcS = idxS;
  int*      dstS = idxS + NEDGES;
  int*      eidx = idxS + 2*NEDGES;

  // eab (bf16 edge_attr, 40.96 MB) aliases outf (40.96 MB): eab is dead before
  // GEMM4 writes outf (stream-ordered), so no extra workspace is consumed.
  uint16_t* eab = (uint16_t*)outf;

  size_t remain = (ws_size > off) ? ws_size - off : 0;
  size_t maxChunk = remain / ((size_t)HID*2*2);    // hb + msgb
  long long chunkE = (long long)(maxChunk & ~(size_t)1023);  // %1024 -> nty%8==0
  if (chunkE > NEDGES) chunkE = NEDGES;
  if (chunkE < 1024) chunkE = 1024;
  uint16_t* hb   = (uint16_t*)alloc((size_t)chunkE*HID*2);
  uint16_t* msgb = (uint16_t*)alloc((size_t)chunkE*HID*2);

  hipMemsetAsync(agg, 0, (size_t)NNODES*HID*4, stream);
  hipMemsetAsync(cnt, 0, (size_t)NNODES*4, stream);
  hipMemsetAsync(flag, 0, 4, stream);

  detect_idx<<<64, 256, 0, stream>>>(ei, flag);
  norm_idx<<<(NEDGES+255)/256, 256, 0, stream>>>(ei, flag, srcN, dstN);
  hist_k<<<(NEDGES+255)/256, 256, 0, stream>>>(dstN, cnt);
  scan_k<<<1, 256, 0, stream>>>(cnt, rp, cur);
  permute_k<<<(NEDGES+255)/256, 256, 0, stream>>>(srcN, dstN, cur, srcS, eidx);
  fill_dstS<<<NNODES, 64, 0, stream>>>(rp, dstS);

  cast_bf16_vec<<<(NNODES*HID/4+255)/256, 256, 0, stream>>>((const float4*)x, (ushort4*)xb, NNODES*HID/4);
  cast_bf16_vec<<<(NEDGES*EDIM/4+255)/256, 256, 0, stream>>>((const float4*)ea, (ushort4*)eab, NEDGES*EDIM/4);

  transpose_cast<<<dim3((KFEAT+255)/256, HID), 256, 0, stream>>>(W1, w1t, KFEAT, HID);
  transpose_cast<<<dim3((HID+255)/256,   HID), 256, 0, stream>>>(W2, w2t, HID, HID);
  transpose_cast<<<dim3((1024+255)/256,  HID), 256, 0, stream>>>(W3, w3t, 1024, HID);
  transpose_cast<<<dim3((HID+255)/256,   HID), 256, 0, stream>>>(W4, w4t, HID, HID);

  // Node GEMMs launch with nty=160 (padded, %8==0 -> XCD grouping active;
  // tiles >= 157 compute clamped rows but write nothing).
  // Fused P|Q = x @ [W1a | W1b]  (N=1024, bf16 output, no bias/act)
  dim3 gpq(1024/128, 160);
  gemm_k<AM_DIR, EP_BF16L, HID, 1><<<gpq, 256, 0, stream>>>(
      xb, nullptr, w1t, b1, PQb, nullptr, KFEAT, 1024, 0, NNODES, 0);

  for (long long e0 = 0; e0 < NEDGES; e0 += chunkE){
    int ce = (int)((NEDGES - e0 < chunkE) ? (NEDGES - e0) : chunkE);
    // EH: h = mish(ea@W1c + P[src] + Q[dst] + b1) -> hb (chunk-local)
    eh_k<<<(ce+31)/32, 256, 0, stream>>>(eab, PQb, idxS, w1t, b1, hb, (int)e0, (int)e0);
    // GEMM2: hb @ W2 -> raw bf16 msgb (bias+mish deferred to gather)
    dim3 g2(HID/128, (ce+127)/128);
    gemm_k<AM_DIR, EP_RAW, HID, 0><<<g2, 256, 0, stream>>>(
        hb, nullptr, w2t, b2, msgb, nullptr, HID, HID, 0, ce, 0);
    // CSR gather-reduce: agg[n] += mish(msg + b2)  (fp32, no atomics)
    gather_agg<<<NNODES, 128, 0, stream>>>(msgb, rp, b2, agg, (int)e0, (int)(e0+ce));
  }

  cast_bf16_vec<<<(NNODES*HID/4+255)/256, 256, 0, stream>>>((const float4*)agg, (ushort4*)aggb, NNODES*HID/4);

  dim3 g3(HID/128, 160);
  gemm_k<AM_NODE, EP_BF16, 1024, 0><<<g3, 256, 0, stream>>>(
      xb, aggb, w3t, b3, ub, nullptr, 1024, HID, 0, NNODES, 0);
  gemm_k<AM_DIR, EP_F32, HID, 0><<<g3, 256, 0, stream>>>(
      ub, nullptr, w4t, b4, nullptr, outf, HID, HID, 0, NNODES, 0);

  resid_ln<<<NNODES, 128, 0, stream>>>(x, outf, gmm, bet, out);
}